// Round 5
// baseline (155.623 us; speedup 1.0000x reference)
//
#include <hip/hip_runtime.h>
#include <stdint.h>

// Causal self-attention: x[8,2048,256] fp32, W_attn[768,256], W_proj[256,256]
// cvt->bf16 (fused), QKV GEMM (K pre-scaled, V transposed), flash attn:
// 32x32x16 MFMA, swapped QK, in-register softmax, 1-tile software pipeline,
// 2-way split-K with LDS combine. proj GEMM.

#define BB 8
#define SS 2048
#define CC 256
#define HH 4
#define DD 64

typedef __attribute__((ext_vector_type(8))) __bf16 bf16x8;
typedef __attribute__((ext_vector_type(4))) __bf16 bf16x4;
typedef __attribute__((ext_vector_type(4))) float f32x4;
typedef __attribute__((ext_vector_type(16))) float f32x16;

#define CM 0.18033688011112042f   // (1/sqrt(64)) * log2(e), folded into K

static __device__ __forceinline__ uint32_t cvtpk(float lo, float hi) {
  uint32_t r;
  asm("v_cvt_pk_bf16_f32 %0, %1, %2" : "=v"(r) : "v"(lo), "v"(hi));
  return r;
}
static __device__ __forceinline__ void pl32swap(uint32_t& a, uint32_t& b) {
  asm("v_permlane32_swap_b32 %0, %1" : "+v"(a), "+v"(b));
}
union PU { uint32_t u[4]; bf16x8 v; };

// ---------------- fused fp32 -> bf16 convert (x, W_attn, W_proj) ------------
__global__ __launch_bounds__(256) void cvt3_kernel(const float* __restrict__ x,
                                                   const float* __restrict__ wa,
                                                   const float* __restrict__ wp,
                                                   __bf16* __restrict__ xb,
                                                   __bf16* __restrict__ wab,
                                                   __bf16* __restrict__ wpb) {
  int i = blockIdx.x * blockDim.x + threadIdx.x;
  const float* in; __bf16* out;
  if (i < 1048576) { in = x; out = xb; }
  else if (i < 1048576 + 49152) { i -= 1048576; in = wa; out = wab; }
  else { i -= 1048576 + 49152; in = wp; out = wpb; }
  float4 v = ((const float4*)in)[i];
  bf16x4 o = { (__bf16)v.x, (__bf16)v.y, (__bf16)v.z, (__bf16)v.w };
  *(bf16x4*)(out + 4 * i) = o;
}

// ---------------- QKV GEMM: qkv = x @ W_attn^T ----------------
// Wave: 32 rows x 64 cols. Block: 4 waves share one otile.
__global__ __launch_bounds__(256) void qkv_gemm(const __bf16* __restrict__ xb,
                                                const __bf16* __restrict__ wb,
                                                __bf16* __restrict__ qb,
                                                __bf16* __restrict__ kb,
                                                __bf16* __restrict__ vtb) {
  const int lane = threadIdx.x & 63;
  const int ln = lane & 15, kg = lane >> 4;
  const int w = threadIdx.x >> 6;
  const int otile = blockIdx.x % 12;
  const int r0 = (blockIdx.x / 12) * 128 + w * 32;
  const int o0 = otile * 64;

  f32x4 acc[2][4] = {};
  for (int c0 = 0; c0 < CC; c0 += 32) {
    bf16x8 a[2], wv[4];
#pragma unroll
    for (int i = 0; i < 2; ++i)
      a[i] = *(const bf16x8*)(xb + (r0 + i * 16 + ln) * CC + c0 + kg * 8);
#pragma unroll
    for (int t = 0; t < 4; ++t)
      wv[t] = *(const bf16x8*)(wb + (o0 + t * 16 + ln) * CC + c0 + kg * 8);
#pragma unroll
    for (int i = 0; i < 2; ++i)
#pragma unroll
      for (int t = 0; t < 4; ++t)
        acc[i][t] = __builtin_amdgcn_mfma_f32_16x16x32_bf16(a[i], wv[t], acc[i][t], 0, 0, 0);
  }
#pragma unroll
  for (int i = 0; i < 2; ++i)
#pragma unroll
    for (int t = 0; t < 4; ++t) {
      int o = o0 + t * 16 + ln;
      int sel = o >> 8;         // 0=q 1=k 2=v
      int oo = o & 255;
      int h = oo >> 6, d = oo & 63;
#pragma unroll
      for (int r = 0; r < 4; ++r) {
        int rout = r0 + i * 16 + kg * 4 + r;
        int b = rout >> 11, s = rout & 2047;
        if (sel == 0)      qb[((b * HH + h) * SS + s) * DD + d] = (__bf16)acc[i][t][r];
        else if (sel == 1) kb[((b * HH + h) * SS + s) * DD + d] = (__bf16)(acc[i][t][r] * CM);
        else               vtb[((b * HH + h) * DD + d) * SS + s] = (__bf16)acc[i][t][r];
      }
    }
}

// ---------------- Flash attention ----------------
// 2048 blocks x 2 waves. Block owns one 32-q chunk; the two waves split the
// key range in halves (online-softmax partials merged via LDS). Each wave
// pipelines: QK(t+1) MFMAs issue before softmax(t) VALU.
#define LOADK(DST, TILE) do { \
  const __bf16* kp_ = K + ((TILE) * 64 + l31) * DD + hi * 8; \
  _Pragma("unroll") for (int s_ = 0; s_ < 4; ++s_) { \
    DST[0][s_] = *(const bf16x8*)(kp_ + s_ * 16); \
    DST[1][s_] = *(const bf16x8*)(kp_ + 32 * DD + s_ * 16); } \
} while (0)

#define LOADV(DST, TILE) do { \
  const __bf16* vp_ = VT + l31 * SS + (TILE) * 64 + hi * 8; \
  _Pragma("unroll") for (int s_ = 0; s_ < 4; ++s_) { \
    DST[0][s_] = *(const bf16x8*)(vp_ + s_ * 16); \
    DST[1][s_] = *(const bf16x8*)(vp_ + 32 * SS + s_ * 16); } \
} while (0)

#define QKM(S0, S1, KA) do { \
  S0 = ZERO; S1 = ZERO; \
  __builtin_amdgcn_s_setprio(1); \
  _Pragma("unroll") for (int s_ = 0; s_ < 4; ++s_) \
    S0 = __builtin_amdgcn_mfma_f32_32x32x16_bf16(KA[0][s_], qf[s_], S0, 0, 0, 0); \
  _Pragma("unroll") for (int s_ = 0; s_ < 4; ++s_) \
    S1 = __builtin_amdgcn_mfma_f32_32x32x16_bf16(KA[1][s_], qf[s_], S1, 0, 0, 0); \
  __builtin_amdgcn_s_setprio(0); \
} while (0)

#define BODY(T, SC0, SC1, SO0, SO1, KC, KO) do { \
  if ((T) + 1 < kt1) { \
    QKM(SO0, SO1, KO); \
    if ((T) + 2 < kt1) LOADK(KC, (T) + 2); \
  } \
  float p[32]; \
  _Pragma("unroll") for (int r_ = 0; r_ < 16; ++r_) { p[r_] = SC0[r_]; p[16 + r_] = SC1[r_]; } \
  if ((T) == ntot - 1) { \
    _Pragma("unroll") for (int r_ = 0; r_ < 16; ++r_) { \
      int crow_ = (r_ & 3) + 8 * (r_ >> 2) + 4 * hi; \
      p[r_]      = (crow_      <= qrel) ? p[r_]      : -1e30f; \
      p[16 + r_] = (crow_ + 32 <= qrel) ? p[16 + r_] : -1e30f; } \
  } \
  float mx[16]; \
  _Pragma("unroll") for (int r_ = 0; r_ < 16; ++r_) mx[r_] = fmaxf(p[r_], p[16 + r_]); \
  _Pragma("unroll") for (int st_ = 8; st_ > 0; st_ >>= 1) \
    _Pragma("unroll") for (int r_ = 0; r_ < 8; ++r_) if (r_ < st_) mx[r_] = fmaxf(mx[r_], mx[r_ + st_]); \
  float tmax = fmaxf(mx[0], __shfl_xor(mx[0], 32)); \
  if (!__all(tmax <= mrun)) { \
    float mnew = fmaxf(mrun, tmax); \
    float al = __builtin_amdgcn_exp2f(mrun - mnew); \
    mrun = mnew; lrun *= al; acc0 *= al; acc1 *= al; \
  } \
  _Pragma("unroll") for (int r_ = 0; r_ < 32; ++r_) p[r_] = __builtin_amdgcn_exp2f(p[r_] - mrun); \
  float sm[16]; \
  _Pragma("unroll") for (int r_ = 0; r_ < 16; ++r_) sm[r_] = p[r_] + p[16 + r_]; \
  _Pragma("unroll") for (int st_ = 8; st_ > 0; st_ >>= 1) \
    _Pragma("unroll") for (int r_ = 0; r_ < 8; ++r_) if (r_ < st_) sm[r_] += sm[r_ + st_]; \
  lrun += sm[0] + __shfl_xor(sm[0], 32); \
  bf16x8 pf[4]; \
  _Pragma("unroll") for (int g_ = 0; g_ < 4; ++g_) { \
    const int o_ = (g_ >> 1) * 16 + (g_ & 1) * 8; \
    uint32_t a_ = cvtpk(p[o_ + 0], p[o_ + 1]); \
    uint32_t b_ = cvtpk(p[o_ + 4], p[o_ + 5]); \
    uint32_t c_ = cvtpk(p[o_ + 2], p[o_ + 3]); \
    uint32_t d_ = cvtpk(p[o_ + 6], p[o_ + 7]); \
    pl32swap(a_, b_); pl32swap(c_, d_); \
    PU u_; u_.u[0] = a_; u_.u[1] = c_; u_.u[2] = b_; u_.u[3] = d_; \
    pf[g_] = u_.v; } \
  __builtin_amdgcn_s_setprio(1); \
  _Pragma("unroll") for (int g_ = 0; g_ < 4; ++g_) \
    acc0 = __builtin_amdgcn_mfma_f32_32x32x16_bf16(vf[0][g_], pf[g_], acc0, 0, 0, 0); \
  _Pragma("unroll") for (int g_ = 0; g_ < 4; ++g_) \
    acc1 = __builtin_amdgcn_mfma_f32_32x32x16_bf16(vf[1][g_], pf[g_], acc1, 0, 0, 0); \
  __builtin_amdgcn_s_setprio(0); \
  if ((T) + 1 < kt1) LOADV(vf, (T) + 1); \
} while (0)

__global__ __launch_bounds__(128, 2) void attn_kernel(const __bf16* __restrict__ qb,
                                                      const __bf16* __restrict__ kb,
                                                      const __bf16* __restrict__ vtb,
                                                      __bf16* __restrict__ yb) {
  __shared__ float lm[2][32];
  __shared__ float lacc[64][33];
  const int lane = threadIdx.x & 63;
  const int l31 = lane & 31;
  const int hi = lane >> 5;
  const int w = threadIdx.x >> 6;      // 0 or 1

  const int bid = blockIdx.x;
  const int xs = bid & 7;              // XCD slot
  const int j = bid >> 3;              // 0..255
  const int bh = xs + 8 * (j & 3);     // 4 bh per XCD -> 4MB KV in L2
  const int c = 63 - (j >> 2);         // longest chunks first
  const int q0w = c * 32;
  const int q = q0w + l31;

  const __bf16* Q = qb + bh * SS * DD;
  const __bf16* K = kb + bh * SS * DD;
  const __bf16* VT = vtb + bh * DD * SS;

  bf16x8 qf[4];
  {
    const __bf16* Qp = Q + q * DD + hi * 8;
#pragma unroll
    for (int s = 0; s < 4; ++s) qf[s] = *(const bf16x8*)(Qp + s * 16);
  }

  const int ntot = (q0w + 95) >> 6;    // 64-key tiles; last = diagonal
  const int seg = (ntot + 1) >> 1;
  const int kt0 = w * seg;
  const int kt1 = min(kt0 + seg, ntot);
  const int qrel = l31 + 32 * (c & 1);

  const f32x16 ZERO = {};
  f32x16 acc0 = ZERO, acc1 = ZERO;
  f32x16 sA0 = ZERO, sA1 = ZERO, sB0 = ZERO, sB1 = ZERO;
  float mrun = -1e30f, lrun = 0.0f;
  bf16x8 kaA[2][4], kaB[2][4], vf[2][4];

  if (kt0 < kt1) {
    LOADK(kaA, kt0);
    LOADV(vf, kt0);
    if (kt0 + 1 < kt1) LOADK(kaB, kt0 + 1);
    QKM(sA0, sA1, kaA);
    int kt = kt0;
    for (; kt + 1 < kt1; kt += 2) {
      BODY(kt,     sA0, sA1, sB0, sB1, kaA, kaB);
      BODY(kt + 1, sB0, sB1, sA0, sA1, kaB, kaA);
    }
    if (kt < kt1) BODY(kt, sA0, sA1, sB0, sB1, kaA, kaB);
  }

  // ---- split-K combine: wave1 -> LDS, wave0 merges + writes y ----
  if (w == 1) {
    if (hi == 0) { lm[0][l31] = mrun; lm[1][l31] = lrun; }
#pragma unroll
    for (int r = 0; r < 16; ++r) {
      int d0 = (r & 3) + 8 * (r >> 2) + 4 * hi;
      lacc[d0][l31] = acc0[r];
      lacc[32 + d0][l31] = acc1[r];
    }
  }
  __syncthreads();
  if (w == 0) {
    float m1 = lm[0][l31], l1 = lm[1][l31];
    float M = fmaxf(mrun, m1);
    float f0 = __builtin_amdgcn_exp2f(mrun - M);
    float f1 = __builtin_amdgcn_exp2f(m1 - M);
    float L = lrun * f0 + l1 * f1;
    float inv = __builtin_amdgcn_rcpf(L);
    const int b = bh >> 2, h = bh & 3;
    __bf16* yrow = yb + (b * SS + q) * CC + h * DD;
#pragma unroll
    for (int g = 0; g < 4; ++g) {
      float a0[4], a1[4];
#pragma unroll
      for (int i2 = 0; i2 < 4; ++i2) {
        int d0 = i2 + 8 * g + 4 * hi;
        a0[i2] = (acc0[g * 4 + i2] * f0 + lacc[d0][l31] * f1) * inv;
        a1[i2] = (acc1[g * 4 + i2] * f0 + lacc[32 + d0][l31] * f1) * inv;
      }
      uint32_t w0 = cvtpk(a0[0], a0[1]);
      uint32_t w1 = cvtpk(a0[2], a0[3]);
      uint2 st0 = { w0, w1 };
      *(uint2*)(yrow + g * 8 + hi * 4) = st0;
      w0 = cvtpk(a1[0], a1[1]);
      w1 = cvtpk(a1[2], a1[3]);
      uint2 st1 = { w0, w1 };
      *(uint2*)(yrow + 32 + g * 8 + hi * 4) = st1;
    }
  }
}

// ---------------- Proj GEMM: out = y @ W_proj^T (fp32 out) ------------------
__global__ __launch_bounds__(256) void proj_gemm(const __bf16* __restrict__ yb,
                                                 const __bf16* __restrict__ wpb,
                                                 float* __restrict__ out) {
  const int lane = threadIdx.x & 63;
  const int ln = lane & 15, kg = lane >> 4;
  const int w = threadIdx.x >> 6;
  const int otile = blockIdx.x & 3;
  const int r0 = (blockIdx.x >> 2) * 128 + w * 32;
  const int o0 = otile * 64;

  f32x4 acc[2][4] = {};
  for (int c0 = 0; c0 < CC; c0 += 32) {
    bf16x8 a[2], wv[4];
#pragma unroll
    for (int i = 0; i < 2; ++i)
      a[i] = *(const bf16x8*)(yb + (r0 + i * 16 + ln) * CC + c0 + kg * 8);
#pragma unroll
    for (int t = 0; t < 4; ++t)
      wv[t] = *(const bf16x8*)(wpb + (o0 + t * 16 + ln) * CC + c0 + kg * 8);
#pragma unroll
    for (int i = 0; i < 2; ++i)
#pragma unroll
      for (int t = 0; t < 4; ++t)
        acc[i][t] = __builtin_amdgcn_mfma_f32_16x16x32_bf16(a[i], wv[t], acc[i][t], 0, 0, 0);
  }
#pragma unroll
  for (int i = 0; i < 2; ++i)
#pragma unroll
    for (int t = 0; t < 4; ++t) {
      int o = o0 + t * 16 + ln;
#pragma unroll
      for (int r = 0; r < 4; ++r) {
        int rout = r0 + i * 16 + kg * 4 + r;
        out[rout * 256 + o] = acc[i][t][r];
      }
    }
}

extern "C" void kernel_launch(void* const* d_in, const int* in_sizes, int n_in,
                              void* d_out, int out_size, void* d_ws, size_t ws_size,
                              hipStream_t stream) {
  const float* x = (const float*)d_in[0];
  const float* Wa = (const float*)d_in[1];
  const float* Wp = (const float*)d_in[2];

  char* ws = (char*)d_ws;
  __bf16* xb  = (__bf16*)(ws);                    // 8 MiB  [B*S][C]
  __bf16* qb  = (__bf16*)(ws + 8388608);          // 8 MiB  [BH][S][D]
  __bf16* kb  = (__bf16*)(ws + 16777216);         // 8 MiB  [BH][S][D] (pre-scaled)
  __bf16* vtb = (__bf16*)(ws + 25165824);         // 8 MiB  [BH][D][S]
  __bf16* yb  = (__bf16*)(ws + 33554432);         // 8 MiB  [B,S,C]
  __bf16* wab = (__bf16*)(ws + 41943040);         // 384 KiB [768][256]
  __bf16* wpb = (__bf16*)(ws + 42336256);         // 128 KiB [256][256]

  cvt3_kernel<<<4352, 256, 0, stream>>>(x, Wa, Wp, xb, wab, wpb);
  qkv_gemm<<<1536, 256, 0, stream>>>(xb, wab, qb, kb, vtb);
  attn_kernel<<<2048, 128, 0, stream>>>(qb, kb, vtb, yb);
  proj_gemm<<<512, 256, 0, stream>>>(yb, wpb, (float*)d_out);
}